// Round 1
// baseline (214.532 us; speedup 1.0000x reference)
//
#include <hip/hip_runtime.h>
#include <hip/hip_bf16.h>
#include <cstdint>

// ---------- types / helpers ----------
typedef __attribute__((ext_vector_type(8))) short  short8;
typedef __attribute__((ext_vector_type(8))) __bf16 bf16x8;
typedef __attribute__((ext_vector_type(4))) float  floatx4;

union Frag { short8 s; bf16x8 b; };

__device__ inline short f2bf(float f) {
    union { float f; unsigned u; } v; v.f = f;
    unsigned r = (v.u + 0x7fffu + ((v.u >> 16) & 1u)) >> 16;  // RNE
    return (short)r;
}
__device__ inline float bf2f(unsigned short u) {
    union { unsigned u; float f; } v; v.u = ((unsigned)u) << 16;
    return v.f;
}
__device__ inline float elu(float x) { return x > 0.f ? x : __expf(x) - 1.f; }

__device__ inline short8 load8_f32_to_bf16(const float* __restrict__ p) {
    float4 f0 = ((const float4*)p)[0];
    float4 f1 = ((const float4*)p)[1];
    short8 r;
    r[0] = f2bf(f0.x); r[1] = f2bf(f0.y); r[2] = f2bf(f0.z); r[3] = f2bf(f0.w);
    r[4] = f2bf(f1.x); r[5] = f2bf(f1.y); r[6] = f2bf(f1.z); r[7] = f2bf(f1.w);
    return r;
}

// ---------- constants ----------
#define B_SZ   4096
#define Z_DIM  256
#define H_DIM  1024
#define OUT_W  33
// option packing offsets (SIZES = [16384,64,4096,64,2048,32])
#define OFF_W1 0
#define OFF_B1 16384
#define OFF_W2 16448
#define OFF_B2 20544
#define OFF_W3 20608
#define OFF_B3 22656
#define OPT_W  22688

// ---------- kernel 1: per-sample hypernetwork (memory-bound, 372 MB) ----------
__global__ __launch_bounds__(256) void hyper_kernel(
    const float* __restrict__ z, const float* __restrict__ opt,
    float* __restrict__ out)
{
    __shared__ __align__(16) float zs[Z_DIM];
    __shared__ __align__(16) float h1[64];
    __shared__ __align__(16) float h2[64];

    const int b = blockIdx.x;
    const int t = threadIdx.x;
    const float* __restrict__ orow = opt + (size_t)b * OPT_W;

    zs[t] = z[(size_t)b * Z_DIM + t];
    __syncthreads();

    // ---- layer 1: [64,256] @ z -> h1[64], relu ----
    {
        const int o = t >> 2, q = t & 3;
        const float* wrow = orow + OFF_W1 + o * 256 + q * 64;
        const float* zp   = zs + q * 64;
        float acc = 0.f;
#pragma unroll
        for (int j = 0; j < 16; ++j) {
            float4 w  = ((const float4*)wrow)[j];
            float4 zv = ((const float4*)zp)[j];
            acc += w.x * zv.x + w.y * zv.y + w.z * zv.z + w.w * zv.w;
        }
        acc += __shfl_xor(acc, 1);
        acc += __shfl_xor(acc, 2);
        if (q == 0) h1[o] = fmaxf(acc + orow[OFF_B1 + o], 0.f);
    }
    __syncthreads();

    // ---- layer 2: [64,64] @ h1 -> h2[64], relu ----
    {
        const int o = t >> 2, q = t & 3;
        const float* wrow = orow + OFF_W2 + o * 64 + q * 16;
        const float* hp   = h1 + q * 16;
        float acc = 0.f;
#pragma unroll
        for (int j = 0; j < 4; ++j) {
            float4 w  = ((const float4*)wrow)[j];
            float4 hv = ((const float4*)hp)[j];
            acc += w.x * hv.x + w.y * hv.y + w.z * hv.z + w.w * hv.w;
        }
        acc += __shfl_xor(acc, 1);
        acc += __shfl_xor(acc, 2);
        if (q == 0) h2[o] = fmaxf(acc + orow[OFF_B2 + o], 0.f);
    }
    __syncthreads();

    // ---- layer 3: [32,64] @ h2 -> action[32] (no activation) ----
    if (t < 128) {
        const int o = t >> 2, q = t & 3;
        const float* wrow = orow + OFF_W3 + o * 64 + q * 16;
        const float* hp   = h2 + q * 16;
        float acc = 0.f;
#pragma unroll
        for (int j = 0; j < 4; ++j) {
            float4 w  = ((const float4*)wrow)[j];
            float4 hv = ((const float4*)hp)[j];
            acc += w.x * hv.x + w.y * hv.y + w.z * hv.z + w.w * hv.w;
        }
        acc += __shfl_xor(acc, 1);
        acc += __shfl_xor(acc, 2);
        if (q == 0) out[(size_t)b * OUT_W + 1 + o] = acc + orow[OFF_B3 + o];
    }
}

// ---------- kernel 2/3: C = elu(A @ B^T + bias), MFMA bf16 ----------
// A: [M, K] (fp32 or bf16), B: [N, K] fp32 row-major (so B^T[k][n] = B[n][k])
// 64x64 tile per block, 4 waves in 2x2, each wave 32x32 via 2x2 mfma 16x16x32.
template<int KTOT, bool ABF16>
__global__ __launch_bounds__(256) void gemm_elu_kernel(
    const void* __restrict__ Av, const float* __restrict__ Bw,
    const float* __restrict__ bias, __hip_bfloat16* __restrict__ Ov)
{
    const int lane = threadIdx.x & 63;
    const int wid  = threadIdx.x >> 6;
    const int wm   = wid >> 1, wn = wid & 1;
    const int m_wave = blockIdx.x * 64 + wm * 32;
    const int n_wave = blockIdx.y * 64 + wn * 32;
    const int lr = lane & 15;          // row (A) / col (B) within 16
    const int lk = (lane >> 4) * 8;    // k offset within 32

    floatx4 acc[2][2] = {};

    for (int k0 = 0; k0 < KTOT; k0 += 32) {
        Frag a[2], bb[2];
#pragma unroll
        for (int sm = 0; sm < 2; ++sm) {
            const int row = m_wave + sm * 16 + lr;
            if constexpr (ABF16) {
                a[sm].s = *(const short8*)((const __hip_bfloat16*)Av +
                                           (size_t)row * KTOT + k0 + lk);
            } else {
                a[sm].s = load8_f32_to_bf16((const float*)Av +
                                            (size_t)row * KTOT + k0 + lk);
            }
        }
#pragma unroll
        for (int sn = 0; sn < 2; ++sn) {
            const int col = n_wave + sn * 16 + lr;
            bb[sn].s = load8_f32_to_bf16(Bw + (size_t)col * KTOT + k0 + lk);
        }
#pragma unroll
        for (int sm = 0; sm < 2; ++sm)
#pragma unroll
            for (int sn = 0; sn < 2; ++sn)
                acc[sm][sn] = __builtin_amdgcn_mfma_f32_16x16x32_bf16(
                    a[sm].b, bb[sn].b, acc[sm][sn], 0, 0, 0);
    }

    // epilogue: D row = (lane>>4)*4 + r, col = lane&15  [verified layout]
#pragma unroll
    for (int sm = 0; sm < 2; ++sm) {
#pragma unroll
        for (int sn = 0; sn < 2; ++sn) {
            const int n = n_wave + sn * 16 + lr;
            const float bv = bias[n];
#pragma unroll
            for (int r = 0; r < 4; ++r) {
                const int m = m_wave + sm * 16 + (lane >> 4) * 4 + r;
                float v = elu(acc[sm][sn][r] + bv);
                Ov[(size_t)m * H_DIM + n] = __float2bfloat16(v);
            }
        }
    }
}

// ---------- kernel 4: value = T2 @ w3^T + b3 ----------
__global__ __launch_bounds__(256) void value_kernel(
    const __hip_bfloat16* __restrict__ t2, const float* __restrict__ w3,
    const float* __restrict__ b3, float* __restrict__ out)
{
    const int b = blockIdx.x, t = threadIdx.x;
    const ushort* row = (const ushort*)(t2 + (size_t)b * H_DIM);
    ushort4 hv = ((const ushort4*)row)[t];     // 4 bf16 per thread
    float4  wv = ((const float4*)w3)[t];
    float acc = bf2f(hv.x) * wv.x + bf2f(hv.y) * wv.y +
                bf2f(hv.z) * wv.z + bf2f(hv.w) * wv.w;
#pragma unroll
    for (int m = 32; m >= 1; m >>= 1) acc += __shfl_xor(acc, m);
    __shared__ float red[4];
    if ((t & 63) == 0) red[t >> 6] = acc;
    __syncthreads();
    if (t == 0)
        out[(size_t)b * OUT_W] = red[0] + red[1] + red[2] + red[3] + b3[0];
}

// ---------- launcher ----------
extern "C" void kernel_launch(void* const* d_in, const int* in_sizes, int n_in,
                              void* d_out, int out_size, void* d_ws, size_t ws_size,
                              hipStream_t stream)
{
    const float* z   = (const float*)d_in[0];
    const float* opt = (const float*)d_in[1];
    const float* w1  = (const float*)d_in[2];
    const float* b1  = (const float*)d_in[3];
    const float* w2  = (const float*)d_in[4];
    const float* b2  = (const float*)d_in[5];
    const float* w3  = (const float*)d_in[6];
    const float* b3  = (const float*)d_in[7];
    float* out = (float*)d_out;

    __hip_bfloat16* T1 = (__hip_bfloat16*)d_ws;                       // 8 MB
    __hip_bfloat16* T2 = (__hip_bfloat16*)((char*)d_ws +
                            (size_t)B_SZ * H_DIM * sizeof(__hip_bfloat16)); // 8 MB

    // hypernet (independent, dominates: 372 MB stream)
    hyper_kernel<<<dim3(B_SZ), dim3(256), 0, stream>>>(z, opt, out);

    // value path: T1 = elu(z @ w1^T + b1)  [M=4096, N=1024, K=256]
    gemm_elu_kernel<Z_DIM, false><<<dim3(B_SZ / 64, H_DIM / 64), dim3(256), 0, stream>>>(
        (const void*)z, w1, b1, T1);

    // T2 = elu(T1 @ w2^T + b2)  [M=4096, N=1024, K=1024]
    gemm_elu_kernel<H_DIM, true><<<dim3(B_SZ / 64, H_DIM / 64), dim3(256), 0, stream>>>(
        (const void*)T1, w2, b2, T2);

    // value = T2 @ w3^T + b3
    value_kernel<<<dim3(B_SZ), dim3(256), 0, stream>>>(T2, w3, b3, out);
}

// Round 2
// 151.553 us; speedup vs baseline: 1.4156x; 1.4156x over previous
//
#include <hip/hip_runtime.h>
#include <hip/hip_bf16.h>
#include <cstdint>

// ---------- types / helpers ----------
typedef __attribute__((ext_vector_type(8))) short  short8;
typedef __attribute__((ext_vector_type(8))) __bf16 bf16x8;
typedef __attribute__((ext_vector_type(4))) float  floatx4;
typedef __attribute__((ext_vector_type(4))) short  short4v;

union Frag { short8 s; bf16x8 b; };

__device__ inline short f2bf(float f) {
    union { float f; unsigned u; } v; v.f = f;
    unsigned r = (v.u + 0x7fffu + ((v.u >> 16) & 1u)) >> 16;  // RNE
    return (short)r;
}
__device__ inline float bf2f(unsigned short u) {
    union { unsigned u; float f; } v; v.u = ((unsigned)u) << 16;
    return v.f;
}
__device__ inline float elu(float x) { return x > 0.f ? x : __expf(x) - 1.f; }

__device__ inline short8 load8_f32_to_bf16(const float* __restrict__ p) {
    float4 f0 = ((const float4*)p)[0];
    float4 f1 = ((const float4*)p)[1];
    short8 r;
    r[0] = f2bf(f0.x); r[1] = f2bf(f0.y); r[2] = f2bf(f0.z); r[3] = f2bf(f0.w);
    r[4] = f2bf(f1.x); r[5] = f2bf(f1.y); r[6] = f2bf(f1.z); r[7] = f2bf(f1.w);
    return r;
}

// ---------- constants ----------
#define B_SZ   4096
#define Z_DIM  256
#define H_DIM  1024
#define OUT_W  33
// option packing offsets (SIZES = [16384,64,4096,64,2048,32])
#define OFF_W1 0
#define OFF_B1 16384
#define OFF_W2 16448
#define OFF_B2 20544
#define OFF_W3 20608
#define OFF_B3 22656
#define OPT_W  22688

#define G1_BLOCKS   1024   // gemm1: (4096/64) x (1024/64)
#define CONV_BLOCKS 64     // w2 -> bf16: 1M elements
#define HYP_OFF     (G1_BLOCKS + CONV_BLOCKS)

// ---------- kernel A: gemm1 + w2 conversion + hypernet, fused ----------
// Block order: compute blocks first so they start early; hyper blocks
// (memory-bound, 372 MB stream) fill the machine and hide gemm1.
__global__ __launch_bounds__(256) void fusedA_kernel(
    const float* __restrict__ z, const float* __restrict__ opt,
    const float* __restrict__ w1, const float* __restrict__ b1,
    const float* __restrict__ w2, const float* __restrict__ b3,
    __hip_bfloat16* __restrict__ T1, __hip_bfloat16* __restrict__ w2bf,
    float* __restrict__ out)
{
    const int blk = blockIdx.x;
    const int t = threadIdx.x;

    if (blk < G1_BLOCKS) {
        // ---- gemm1: T1 = elu(z @ w1^T + b1), 64x64 tile, K=256 ----
        const int lane = t & 63, wid = t >> 6;
        const int wm = wid >> 1, wn = wid & 1;
        const int m_wave = (blk >> 4) * 64 + wm * 32;
        const int n_wave = (blk & 15) * 64 + wn * 32;
        const int lr = lane & 15, lk = (lane >> 4) * 8;

        floatx4 acc[2][2] = {};
        for (int k0 = 0; k0 < Z_DIM; k0 += 32) {
            Frag a[2], bb[2];
#pragma unroll
            for (int sm = 0; sm < 2; ++sm)
                a[sm].s = load8_f32_to_bf16(z + (size_t)(m_wave + sm * 16 + lr) * Z_DIM + k0 + lk);
#pragma unroll
            for (int sn = 0; sn < 2; ++sn)
                bb[sn].s = load8_f32_to_bf16(w1 + (size_t)(n_wave + sn * 16 + lr) * Z_DIM + k0 + lk);
#pragma unroll
            for (int sm = 0; sm < 2; ++sm)
#pragma unroll
                for (int sn = 0; sn < 2; ++sn)
                    acc[sm][sn] = __builtin_amdgcn_mfma_f32_16x16x32_bf16(
                        a[sm].b, bb[sn].b, acc[sm][sn], 0, 0, 0);
        }
#pragma unroll
        for (int sm = 0; sm < 2; ++sm)
#pragma unroll
            for (int sn = 0; sn < 2; ++sn) {
                const int n = n_wave + sn * 16 + lr;
                const float bv = b1[n];
#pragma unroll
                for (int r = 0; r < 4; ++r) {
                    const int m = m_wave + sm * 16 + (lane >> 4) * 4 + r;
                    T1[(size_t)m * H_DIM + n] = __float2bfloat16(elu(acc[sm][sn][r] + bv));
                }
            }
    } else if (blk < HYP_OFF) {
        // ---- w2 -> bf16 (1M elems as 256K float4), coalesced ----
        const int gtid = (blk - G1_BLOCKS) * 256 + t;  // 0..16383
#pragma unroll
        for (int i = 0; i < 16; ++i) {
            const int v = gtid + i * 16384;            // float4 index < 262144
            float4 f = ((const float4*)w2)[v];
            short4v s;
            s[0] = f2bf(f.x); s[1] = f2bf(f.y); s[2] = f2bf(f.z); s[3] = f2bf(f.w);
            ((short4v*)w2bf)[v] = s;
        }
    } else {
        // ---- hypernet: one block per sample ----
        __shared__ __align__(16) float zs[Z_DIM];
        __shared__ __align__(16) float h1[64];
        __shared__ __align__(16) float h2[64];

        const int b = blk - HYP_OFF;
        const float* __restrict__ orow = opt + (size_t)b * OPT_W;

        if (t == 0) out[(size_t)b * OUT_W] = b3[0];  // init for gemm2's value atomics
        zs[t] = z[(size_t)b * Z_DIM + t];
        __syncthreads();

        // layer 1: [64,256] @ z -> h1, relu
        {
            const int o = t >> 2, q = t & 3;
            const float* wrow = orow + OFF_W1 + o * 256 + q * 64;
            const float* zp   = zs + q * 64;
            float acc = 0.f;
#pragma unroll
            for (int j = 0; j < 16; ++j) {
                float4 w  = ((const float4*)wrow)[j];
                float4 zv = ((const float4*)zp)[j];
                acc += w.x * zv.x + w.y * zv.y + w.z * zv.z + w.w * zv.w;
            }
            acc += __shfl_xor(acc, 1);
            acc += __shfl_xor(acc, 2);
            if (q == 0) h1[o] = fmaxf(acc + orow[OFF_B1 + o], 0.f);
        }
        __syncthreads();

        // layer 2: [64,64] @ h1 -> h2, relu
        {
            const int o = t >> 2, q = t & 3;
            const float* wrow = orow + OFF_W2 + o * 64 + q * 16;
            const float* hp   = h1 + q * 16;
            float acc = 0.f;
#pragma unroll
            for (int j = 0; j < 4; ++j) {
                float4 w  = ((const float4*)wrow)[j];
                float4 hv = ((const float4*)hp)[j];
                acc += w.x * hv.x + w.y * hv.y + w.z * hv.z + w.w * hv.w;
            }
            acc += __shfl_xor(acc, 1);
            acc += __shfl_xor(acc, 2);
            if (q == 0) h2[o] = fmaxf(acc + orow[OFF_B2 + o], 0.f);
        }
        __syncthreads();

        // layer 3: [32,64] @ h2 -> action[32]
        if (t < 128) {
            const int o = t >> 2, q = t & 3;
            const float* wrow = orow + OFF_W3 + o * 64 + q * 16;
            const float* hp   = h2 + q * 16;
            float acc = 0.f;
#pragma unroll
            for (int j = 0; j < 4; ++j) {
                float4 w  = ((const float4*)wrow)[j];
                float4 hv = ((const float4*)hp)[j];
                acc += w.x * hv.x + w.y * hv.y + w.z * hv.z + w.w * hv.w;
            }
            acc += __shfl_xor(acc, 1);
            acc += __shfl_xor(acc, 2);
            if (q == 0) out[(size_t)b * OUT_W + 1 + o] = acc + orow[OFF_B3 + o];
        }
    }
}

// ---------- kernel B: gemm2 (bf16 x bf16) + fused value epilogue ----------
// 128x128 tile, 4 waves 2x2, each wave 64x64 (4x4 frags of 16x16x32).
// No T2 store: value partial = sum_n elu(acc+b2[n]) * w3[n], atomicAdd to out col 0.
__global__ __launch_bounds__(256) void gemm2_value_kernel(
    const __hip_bfloat16* __restrict__ T1, const __hip_bfloat16* __restrict__ w2bf,
    const float* __restrict__ b2, const float* __restrict__ w3,
    float* __restrict__ out)
{
    const int lane = threadIdx.x & 63, wid = threadIdx.x >> 6;
    const int wm = wid >> 1, wn = wid & 1;
    const int m_wave = blockIdx.x * 128 + wm * 64;
    const int n_wave = blockIdx.y * 128 + wn * 64;
    const int lr = lane & 15, lk = (lane >> 4) * 8;

    const ushort* __restrict__ A  = (const ushort*)T1;
    const ushort* __restrict__ Bm = (const ushort*)w2bf;

    floatx4 acc[4][4] = {};
    for (int k0 = 0; k0 < H_DIM; k0 += 32) {
        Frag a[4], bb[4];
#pragma unroll
        for (int sm = 0; sm < 4; ++sm)
            a[sm].s = *(const short8*)(A + (size_t)(m_wave + sm * 16 + lr) * H_DIM + k0 + lk);
#pragma unroll
        for (int sn = 0; sn < 4; ++sn)
            bb[sn].s = *(const short8*)(Bm + (size_t)(n_wave + sn * 16 + lr) * H_DIM + k0 + lk);
#pragma unroll
        for (int sm = 0; sm < 4; ++sm)
#pragma unroll
            for (int sn = 0; sn < 4; ++sn)
                acc[sm][sn] = __builtin_amdgcn_mfma_f32_16x16x32_bf16(
                    a[sm].b, bb[sn].b, acc[sm][sn], 0, 0, 0);
    }

    // per-lane bias and w3 for the 4 col-fragments
    float bias_v[4], w3_v[4];
#pragma unroll
    for (int sn = 0; sn < 4; ++sn) {
        const int n = n_wave + sn * 16 + lr;
        bias_v[sn] = b2[n];
        w3_v[sn]   = w3[n];
    }

#pragma unroll
    for (int sm = 0; sm < 4; ++sm) {
#pragma unroll
        for (int r = 0; r < 4; ++r) {
            float rowsum = 0.f;
#pragma unroll
            for (int sn = 0; sn < 4; ++sn)
                rowsum += elu(acc[sm][sn][r] + bias_v[sn]) * w3_v[sn];
            // reduce across the 16 col-lanes (lr); preserves lane>>4 groups
            rowsum += __shfl_xor(rowsum, 1);
            rowsum += __shfl_xor(rowsum, 2);
            rowsum += __shfl_xor(rowsum, 4);
            rowsum += __shfl_xor(rowsum, 8);
            if (lr == 0) {
                const int m = m_wave + sm * 16 + (lane >> 4) * 4 + r;
                atomicAdd(out + (size_t)m * OUT_W, rowsum);
            }
        }
    }
}

// ---------- launcher ----------
extern "C" void kernel_launch(void* const* d_in, const int* in_sizes, int n_in,
                              void* d_out, int out_size, void* d_ws, size_t ws_size,
                              hipStream_t stream)
{
    const float* z   = (const float*)d_in[0];
    const float* opt = (const float*)d_in[1];
    const float* w1  = (const float*)d_in[2];
    const float* b1  = (const float*)d_in[3];
    const float* w2  = (const float*)d_in[4];
    const float* b2  = (const float*)d_in[5];
    const float* w3  = (const float*)d_in[6];
    const float* b3  = (const float*)d_in[7];
    float* out = (float*)d_out;

    __hip_bfloat16* T1   = (__hip_bfloat16*)d_ws;  // 8 MB
    __hip_bfloat16* w2bf = (__hip_bfloat16*)((char*)d_ws +
                             (size_t)B_SZ * H_DIM * sizeof(__hip_bfloat16));  // 2 MB

    // kernel A: gemm1 (early blocks) + w2 conversion + hypernet (bulk)
    fusedA_kernel<<<dim3(HYP_OFF + B_SZ), dim3(256), 0, stream>>>(
        z, opt, w1, b1, w2, b3, T1, w2bf, out);

    // kernel B: gemm2 + value fused
    gemm2_value_kernel<<<dim3(B_SZ / 128, H_DIM / 128), dim3(256), 0, stream>>>(
        T1, w2bf, b2, w3, out);
}

// Round 3
// 137.894 us; speedup vs baseline: 1.5558x; 1.0991x over previous
//
#include <hip/hip_runtime.h>
#include <hip/hip_bf16.h>
#include <cstdint>

// ---------- types / helpers ----------
typedef __attribute__((ext_vector_type(8))) short  short8;
typedef __attribute__((ext_vector_type(8))) __bf16 bf16x8;
typedef __attribute__((ext_vector_type(4))) float  floatx4;
typedef __attribute__((ext_vector_type(4))) short  short4v;

union Frag { short8 s; bf16x8 b; };

__device__ inline short f2bf(float f) {
    union { float f; unsigned u; } v; v.f = f;
    unsigned r = (v.u + 0x7fffu + ((v.u >> 16) & 1u)) >> 16;  // RNE
    return (short)r;
}
__device__ inline float elu(float x) { return x > 0.f ? x : __expf(x) - 1.f; }

__device__ inline short8 load8_f32_to_bf16(const float* __restrict__ p) {
    float4 f0 = ((const float4*)p)[0];
    float4 f1 = ((const float4*)p)[1];
    short8 r;
    r[0] = f2bf(f0.x); r[1] = f2bf(f0.y); r[2] = f2bf(f0.z); r[3] = f2bf(f0.w);
    r[4] = f2bf(f1.x); r[5] = f2bf(f1.y); r[6] = f2bf(f1.z); r[7] = f2bf(f1.w);
    return r;
}

// ---------- constants ----------
#define B_SZ   4096
#define Z_DIM  256
#define H_DIM  1024
#define OUT_W  33
// option packing offsets (SIZES = [16384,64,4096,64,2048,32])
#define OFF_W1 0
#define OFF_B1 16384
#define OFF_W2 16448
#define OFF_B2 20544
#define OFF_W3 20608
#define OFF_B3 22656
#define OPT_W  22688

#define HYP_K1 1024                 // hyper samples done in kernel 1
#define G_BLOCKS 256                // 128x128 tiles: (4096/128) x (1024/128)
#define CONV_BLOCKS 64

// ---------- shared 128x128 MFMA gemm tile (4 waves 2x2, 4x4 frags) ----------
// C = elu(A @ B^T + bias). If VEPI: no C store; instead atomicAdd
// sum_n elu(...)*w3[n] into out[m*OUT_W]. Else: store bf16 C into T.
template<int KTOT, bool ACONV, bool BCONV, bool VEPI>
__device__ __forceinline__ void gemm_tile(
    const void* __restrict__ Av, const void* __restrict__ Bv,
    const float* __restrict__ bias, const float* __restrict__ w3,
    __hip_bfloat16* __restrict__ T, float* __restrict__ out,
    int bm, int bn, int tid)
{
    const int lane = tid & 63, wid = tid >> 6;
    const int wm = wid >> 1, wn = wid & 1;
    const int m_wave = bm * 128 + wm * 64;
    const int n_wave = bn * 128 + wn * 64;
    const int lr = lane & 15, lk = (lane >> 4) * 8;

    floatx4 acc[4][4] = {};
    for (int k0 = 0; k0 < KTOT; k0 += 32) {
        Frag a[4], bb[4];
#pragma unroll
        for (int sm = 0; sm < 4; ++sm) {
            const size_t off = (size_t)(m_wave + sm * 16 + lr) * KTOT + k0 + lk;
            if constexpr (ACONV) a[sm].s = load8_f32_to_bf16((const float*)Av + off);
            else                 a[sm].s = *(const short8*)((const ushort*)Av + off);
        }
#pragma unroll
        for (int sn = 0; sn < 4; ++sn) {
            const size_t off = (size_t)(n_wave + sn * 16 + lr) * KTOT + k0 + lk;
            if constexpr (BCONV) bb[sn].s = load8_f32_to_bf16((const float*)Bv + off);
            else                 bb[sn].s = *(const short8*)((const ushort*)Bv + off);
        }
#pragma unroll
        for (int sm = 0; sm < 4; ++sm)
#pragma unroll
            for (int sn = 0; sn < 4; ++sn)
                acc[sm][sn] = __builtin_amdgcn_mfma_f32_16x16x32_bf16(
                    a[sm].b, bb[sn].b, acc[sm][sn], 0, 0, 0);
    }

    if constexpr (VEPI) {
        float bias_v[4], w3_v[4];
#pragma unroll
        for (int sn = 0; sn < 4; ++sn) {
            const int n = n_wave + sn * 16 + lr;
            bias_v[sn] = bias[n];
            w3_v[sn]   = w3[n];
        }
#pragma unroll
        for (int sm = 0; sm < 4; ++sm) {
#pragma unroll
            for (int r = 0; r < 4; ++r) {
                float rowsum = 0.f;
#pragma unroll
                for (int sn = 0; sn < 4; ++sn)
                    rowsum += elu(acc[sm][sn][r] + bias_v[sn]) * w3_v[sn];
                rowsum += __shfl_xor(rowsum, 1);
                rowsum += __shfl_xor(rowsum, 2);
                rowsum += __shfl_xor(rowsum, 4);
                rowsum += __shfl_xor(rowsum, 8);
                if (lr == 0) {
                    const int m = m_wave + sm * 16 + (lane >> 4) * 4 + r;
                    atomicAdd(out + (size_t)m * OUT_W, rowsum);
                }
            }
        }
    } else {
#pragma unroll
        for (int sm = 0; sm < 4; ++sm)
#pragma unroll
            for (int sn = 0; sn < 4; ++sn) {
                const int n = n_wave + sn * 16 + lr;
                const float bv = bias[n];
#pragma unroll
                for (int r = 0; r < 4; ++r) {
                    const int m = m_wave + sm * 16 + (lane >> 4) * 4 + r;
                    T[(size_t)m * H_DIM + n] = __float2bfloat16(elu(acc[sm][sn][r] + bv));
                }
            }
    }
}

// ---------- hypernet, fully wave-coalesced ----------
// All weight loads: wave reads contiguous 1KB per instruction.
__device__ __forceinline__ void hyper_sample(
    const float* __restrict__ z, const float* __restrict__ opt,
    float* __restrict__ out, int b, int tid,
    float* __restrict__ h1, float* __restrict__ h2)
{
    const int lane = tid & 63, w = tid >> 6;
    const float* __restrict__ orow = opt + (size_t)b * OPT_W;

    // this lane's activation slice: cols 4*lane..4*lane+3 of z-row
    const float4 z4 = *(const float4*)(z + (size_t)b * Z_DIM + 4 * lane);

    // ---- layer 1: [64,256]; wave w -> rows 16w..16w+15 (16KB contiguous) ----
    {
        const float4* wbase = (const float4*)(orow + OFF_W1 + w * 16 * Z_DIM);
        float4 wv[16];
#pragma unroll
        for (int j = 0; j < 16; ++j) wv[j] = wbase[j * 64 + lane];  // row j, cols 4*lane
#pragma unroll
        for (int j = 0; j < 16; ++j) {
            float p = wv[j].x * z4.x + wv[j].y * z4.y + wv[j].z * z4.z + wv[j].w * z4.w;
            p += __shfl_xor(p, 1);  p += __shfl_xor(p, 2);
            p += __shfl_xor(p, 4);  p += __shfl_xor(p, 8);
            p += __shfl_xor(p, 16); p += __shfl_xor(p, 32);
            if (lane == 0) {
                const int r = 16 * w + j;
                h1[r] = fmaxf(p + orow[OFF_B1 + r], 0.f);
            }
        }
    }
    __syncthreads();

    // ---- layer 2: [64,64]; wave w -> rows 16w..16w+15 (4KB contiguous) ----
    {
        const float4 h1v = *(const float4*)(h1 + 4 * (lane & 15));
        const float4* wbase = (const float4*)(orow + OFF_W2 + w * 16 * 64);
        float4 wv[4];
#pragma unroll
        for (int j = 0; j < 4; ++j) wv[j] = wbase[j * 64 + lane];  // row j*4+(lane>>4), cols 4*(lane&15)
#pragma unroll
        for (int j = 0; j < 4; ++j) {
            float p = wv[j].x * h1v.x + wv[j].y * h1v.y + wv[j].z * h1v.z + wv[j].w * h1v.w;
            p += __shfl_xor(p, 1); p += __shfl_xor(p, 2);
            p += __shfl_xor(p, 4); p += __shfl_xor(p, 8);
            if ((lane & 15) == 0) {
                const int r = 16 * w + j * 4 + (lane >> 4);
                h2[r] = fmaxf(p + orow[OFF_B2 + r], 0.f);
            }
        }
    }
    __syncthreads();

    // ---- layer 3: [32,64]; wave w -> rows 8w..8w+7 (2KB contiguous) ----
    {
        const float4 h2v = *(const float4*)(h2 + 4 * (lane & 15));
        const float4* wbase = (const float4*)(orow + OFF_W3 + w * 8 * 64);
        float4 wv[2];
#pragma unroll
        for (int j = 0; j < 2; ++j) wv[j] = wbase[j * 64 + lane];
#pragma unroll
        for (int j = 0; j < 2; ++j) {
            float p = wv[j].x * h2v.x + wv[j].y * h2v.y + wv[j].z * h2v.z + wv[j].w * h2v.w;
            p += __shfl_xor(p, 1); p += __shfl_xor(p, 2);
            p += __shfl_xor(p, 4); p += __shfl_xor(p, 8);
            if ((lane & 15) == 0) {
                const int r = 8 * w + j * 4 + (lane >> 4);
                out[(size_t)b * OUT_W + 1 + r] = p + orow[OFF_B3 + r];
            }
        }
    }
}

// ---------- kernel 1: gemm1 + w2conv + col0-init + hyper[0:HYP_K1) ----------
__global__ __launch_bounds__(256) void k1_kernel(
    const float* __restrict__ z, const float* __restrict__ opt,
    const float* __restrict__ w1, const float* __restrict__ b1,
    const float* __restrict__ w2, const float* __restrict__ b3,
    __hip_bfloat16* __restrict__ T1, __hip_bfloat16* __restrict__ w2bf,
    float* __restrict__ out)
{
    __shared__ float h1[64], h2[64];
    const int blk = blockIdx.x, t = threadIdx.x;

    if (blk < G_BLOCKS) {
        gemm_tile<Z_DIM, true, true, false>(z, w1, b1, nullptr, T1, nullptr,
                                            blk >> 3, blk & 7, t);
    } else if (blk < G_BLOCKS + CONV_BLOCKS) {
        const int gtid = (blk - G_BLOCKS) * 256 + t;  // 0..16383
        if (gtid < B_SZ) out[(size_t)gtid * OUT_W] = b3[0];  // init value col
#pragma unroll
        for (int i = 0; i < 16; ++i) {
            const int v = gtid + i * 16384;           // float4 index < 262144
            float4 f = ((const float4*)w2)[v];
            short4v s;
            s[0] = f2bf(f.x); s[1] = f2bf(f.y); s[2] = f2bf(f.z); s[3] = f2bf(f.w);
            ((short4v*)w2bf)[v] = s;
        }
    } else {
        hyper_sample(z, opt, out, blk - (G_BLOCKS + CONV_BLOCKS), t, h1, h2);
    }
}

// ---------- kernel 2: gemm2+value + hyper[HYP_K1:B_SZ) ----------
__global__ __launch_bounds__(256) void k2_kernel(
    const float* __restrict__ z, const float* __restrict__ opt,
    const __hip_bfloat16* __restrict__ T1, const __hip_bfloat16* __restrict__ w2bf,
    const float* __restrict__ b2, const float* __restrict__ w3,
    float* __restrict__ out)
{
    __shared__ float h1[64], h2[64];
    const int blk = blockIdx.x, t = threadIdx.x;

    if (blk < G_BLOCKS) {
        gemm_tile<H_DIM, false, false, true>(T1, w2bf, b2, w3, nullptr, out,
                                             blk >> 3, blk & 7, t);
    } else {
        hyper_sample(z, opt, out, HYP_K1 + (blk - G_BLOCKS), t, h1, h2);
    }
}

// ---------- launcher ----------
extern "C" void kernel_launch(void* const* d_in, const int* in_sizes, int n_in,
                              void* d_out, int out_size, void* d_ws, size_t ws_size,
                              hipStream_t stream)
{
    const float* z   = (const float*)d_in[0];
    const float* opt = (const float*)d_in[1];
    const float* w1  = (const float*)d_in[2];
    const float* b1  = (const float*)d_in[3];
    const float* w2  = (const float*)d_in[4];
    const float* b2  = (const float*)d_in[5];
    const float* w3  = (const float*)d_in[6];
    const float* b3  = (const float*)d_in[7];
    float* out = (float*)d_out;

    __hip_bfloat16* T1   = (__hip_bfloat16*)d_ws;  // 8 MB
    __hip_bfloat16* w2bf = (__hip_bfloat16*)((char*)d_ws +
                             (size_t)B_SZ * H_DIM * sizeof(__hip_bfloat16));  // 2 MB

    k1_kernel<<<dim3(G_BLOCKS + CONV_BLOCKS + HYP_K1), dim3(256), 0, stream>>>(
        z, opt, w1, b1, w2, b3, T1, w2bf, out);

    k2_kernel<<<dim3(G_BLOCKS + (B_SZ - HYP_K1)), dim3(256), 0, stream>>>(
        z, opt, T1, w2bf, b2, w3, out);
}